// Round 6
// baseline (131.850 us; speedup 1.0000x reference)
//
#include <hip/hip_runtime.h>

// LearnedTaskSpecificLinear: out[n,o] = sum_i x[n,i] * W[task_ids[n], i, o]
// x: [2048,512] f32, task_ids: [2048] i32, W: [64,512,512] f32, out: [2048,512] f32
//
// Round 6: DIAGNOSTIC — R5 algorithm, body executed twice (idempotent: same
// values recomputed/restored; memory clobber forces real re-loads). Purpose:
// dispatch duration ~2x t_k > 40 us so the kernel enters the profiled top-5
// and we finally see its counters (VALUBusy / MfmaUtil / LDS conflicts /
// occupancy / hbm_gbps). total(R6) - total(R5) = t_k independently.
//
//   grid (16 col-chunks of 32, 64 tasks) x 256 thr (4 waves), ~34 KB LDS.
//   Per block: per-wave ballot rowlist scan, W staged to LDS f16 once,
//   XOR-swizzled octets (conflict-free b128 write+read), A-frags straight
//   from global x with in-register f32->f16, no cross-wave reduce.

#define NDIM 512
#define KDIM 512
#define NCOL 32

typedef _Float16 f16x8 __attribute__((ext_vector_type(8)));
typedef float    f32x4 __attribute__((ext_vector_type(4)));

__global__ __launch_bounds__(256) void k_fused(
    const float* __restrict__ x,
    const int*   __restrict__ tids,
    const float* __restrict__ W,
    float*       __restrict__ out,
    int n_rows)
{
    const int tid  = threadIdx.x;
    const int lane = tid & 63;
    const int wv   = tid >> 6;
    const int c0   = blockIdx.x * NCOL;
    const int task = blockIdx.y;

    __shared__ __align__(16) _Float16 Wt[NCOL * KDIM];   // 32 KB, [c][k] swizzled
    __shared__ unsigned short rlw[4 * 128];              // per-wave lists
    __shared__ unsigned short rl[256];                   // compacted list
    __shared__ int wcnt[4];

    const int sc4   = (tid & 7) * 4;      // 4-col group
    const int obase = tid >> 3;           // k-octet 0..31 (+32 for 2nd half)
    const float* Wg = W + (size_t)task * KDIM * NDIM + c0;
    const int ml = lane & 15;
    const int q  = lane >> 4;

    for (int rep = 0; rep < 2; ++rep) {
        __syncthreads();                   // protect LDS reuse across reps
        asm volatile("" ::: "memory");     // force re-issue of global loads

        // ---- issue tids loads first (8 per lane, this wave's quarter)
        int trow[8], tval[8];
        #pragma unroll
        for (int it = 0; it < 8; ++it) {
            trow[it] = wv * 512 + it * 64 + lane;
            tval[it] = (trow[it] < n_rows) ? tids[trow[it]] : -1;
        }

        // ---- issue all W loads (latency hidden behind the scan)
        float4 wr[16];
        #pragma unroll
        for (int j = 0; j < 8; ++j)
            wr[j] = *(const float4*)(Wg + (size_t)(obase * 8 + j) * NDIM + sc4);
        #pragma unroll
        for (int j = 0; j < 8; ++j)
            wr[8 + j] = *(const float4*)(Wg + (size_t)((obase + 32) * 8 + j) * NDIM + sc4);

        // ---- ballot scan of this wave's quarter
        int cloc = 0;
        #pragma unroll
        for (int it = 0; it < 8; ++it) {
            const bool m = (tval[it] == task);
            const unsigned long long bal = __ballot(m);
            const int rank = __popcll(bal & ((1ull << lane) - 1ull));
            if (m) rlw[wv * 128 + cloc + rank] = (unsigned short)trow[it];
            cloc += __popcll(bal);
        }
        if (lane == 0) wcnt[wv] = cloc;

        // ---- W f32->f16 + swizzled LDS write (4 b128 per half per thread)
        #pragma unroll
        for (int h = 0; h < 2; ++h) {
            const int oct = obase + h * 32;
            #pragma unroll
            for (int j2 = 0; j2 < 4; ++j2) {
                f16x8 h8;
                #pragma unroll
                for (int j = 0; j < 8; ++j)
                    h8[j] = (_Float16)(((const float*)&wr[h * 8 + j])[j2]);
                const int c  = sc4 + j2;
                const int po = oct ^ (c & 7);
                *(f16x8*)&Wt[c * KDIM + po * 8] = h8;
            }
        }

        __syncthreads();

        // ---- compact the 4 wave-lists into rl[]
        const int n0 = wcnt[0], n1 = wcnt[1], n2 = wcnt[2], n3 = wcnt[3];
        const int o1 = n0, o2 = n0 + n1, o3 = o2 + n2;
        const int count = o3 + n3;
        if (tid < count && tid < 256) {
            int w, base;
            if (tid < o1)      { w = 0; base = 0;  }
            else if (tid < o2) { w = 1; base = o1; }
            else if (tid < o3) { w = 2; base = o2; }
            else               { w = 3; base = o3; }
            rl[tid] = rlw[w * 128 + tid - base];
        }
        __syncthreads();

        if (count == 0) return;   // block-uniform; Poisson(32) => ~never

        for (int g0 = 0; g0 < count; g0 += 64) {
            const int rr = g0 + wv * 16 + ml;
            const int rowid = rl[(rr < count) ? rr : 0];
            const float* xrow = x + (size_t)rowid * KDIM;

            f32x4 acc[2] = {};
            #pragma unroll
            for (int p = 0; p < 2; ++p) {
                const int kb = p * 256;
                float4 xa[16];
                #pragma unroll
                for (int ks = 0; ks < 8; ++ks) {
                    xa[2 * ks]     = *(const float4*)(xrow + kb + ks * 32 + q * 8);
                    xa[2 * ks + 1] = *(const float4*)(xrow + kb + ks * 32 + q * 8 + 4);
                }
                #pragma unroll
                for (int ks = 0; ks < 8; ++ks) {
                    f16x8 af;
                    const float* a0 = (const float*)&xa[2 * ks];
                    #pragma unroll
                    for (int j = 0; j < 8; ++j) af[j] = (_Float16)a0[j];
                    #pragma unroll
                    for (int ct = 0; ct < 2; ++ct) {
                        const int cB = ct * 16 + ml;
                        const int po = (p * 32 + ks * 4 + q) ^ (cB & 7);
                        const f16x8 bf = *(const f16x8*)&Wt[cB * KDIM + po * 8];
                        acc[ct] = __builtin_amdgcn_mfma_f32_16x16x32_f16(af, bf, acc[ct], 0, 0, 0);
                    }
                }
            }

            // ---- store: C/D row = q*4+rg (wave-local), col = ct*16+ml
            #pragma unroll
            for (int rg = 0; rg < 4; ++rg) {
                const int rr2 = g0 + wv * 16 + q * 4 + rg;
                if (rr2 < count) {
                    float* op = out + (size_t)rl[rr2] * NDIM + c0 + ml;
                    op[0]  = acc[0][rg];
                    op[16] = acc[1][rg];
                }
            }
        }
    }
}

extern "C" void kernel_launch(void* const* d_in, const int* in_sizes, int n_in,
                              void* d_out, int out_size, void* d_ws, size_t ws_size,
                              hipStream_t stream) {
    const float* x    = (const float*)d_in[0];
    const int*   tids = (const int*)d_in[1];
    const float* W    = (const float*)d_in[2];
    float*       out  = (float*)d_out;
    const int n_rows  = in_sizes[1];   // 2048

    k_fused<<<dim3(NDIM / NCOL, 64), dim3(256), 0, stream>>>(x, tids, W, out, n_rows);
}

// Round 7
// 131.637 us; speedup vs baseline: 1.0016x; 1.0016x over previous
//
#include <hip/hip_runtime.h>

// LearnedTaskSpecificLinear: out[n,o] = sum_i x[n,i] * W[task_ids[n], i, o]
// x: [2048,512] f32, task_ids: [2048] i32, W: [64,512,512] f32, out: [2048,512] f32
//
// Round 7: wave-autonomous direct-from-global MFMA (R6 diagnosis: latency-
// chain-bound at 3 waves/CU; LDS W-staging + barriers were the chain).
//   grid (32 col-chunks of 16, 64 tasks) = 2048 blocks x 256 thr (4 waves).
//   Block prologue: cooperative ballot scan of tids (wave w scans quarter)
//   -> compacted rowlist in LDS; 2 barriers total, then waves INDEPENDENT.
//   Wave w = row-group rg (16 rows) x 16 cols x K=512: 16x mfma_f32_16x16x32_f16.
//   A-frags: lane(ml,q) float4-loads x[rl[rg*16+ml]][k0+q*8(+4)] (global).
//   B-frags: lane(ml,q) dword-loads W[k0+q*8+j][c0+ml] (global; 4x64B
//   coalesced segments per instr, full 128B lines consumed per wave; sibling
//   waves L1-hit the same 32KB slice). f32->f16 RNE in-register. No LDS for
//   data, no barriers after prologue, empty waves exit immediately.

#define NDIM 512
#define KDIM 512
#define NCOL 16

typedef _Float16 f16x8 __attribute__((ext_vector_type(8)));
typedef float    f32x4 __attribute__((ext_vector_type(4)));

__global__ __launch_bounds__(256, 4) void k_fused(
    const float* __restrict__ x,
    const int*   __restrict__ tids,
    const float* __restrict__ W,
    float*       __restrict__ out,
    int n_rows)
{
    const int tid  = threadIdx.x;
    const int lane = tid & 63;
    const int wv   = tid >> 6;
    const int c0   = blockIdx.x * NCOL;
    const int task = blockIdx.y;

    __shared__ unsigned short rlw[4 * 512];   // per-wave lists (any distribution safe)
    __shared__ unsigned short rl[2048];       // compacted
    __shared__ int wcnt[4];

    // ---- cooperative ballot scan: wave w scans rows [w*512, w*512+512)
    {
        int cloc = 0;
        #pragma unroll
        for (int it = 0; it < 8; ++it) {
            const int r = wv * 512 + it * 64 + lane;
            const bool m = (r < n_rows) && (tids[r] == task);
            const unsigned long long bal = __ballot(m);
            const int rank = __popcll(bal & ((1ull << lane) - 1ull));
            if (m) rlw[wv * 512 + cloc + rank] = (unsigned short)r;
            cloc += __popcll(bal);
        }
        if (lane == 0) wcnt[wv] = cloc;
    }
    __syncthreads();
    const int n0 = wcnt[0], n1 = wcnt[1], n2 = wcnt[2];
    const int o1 = n0, o2 = n0 + n1, o3 = o2 + n2;
    const int count = o3 + wcnt[3];
    for (int i = tid; i < count; i += 256) {
        int w, base;
        if (i < o1)      { w = 0; base = 0;  }
        else if (i < o2) { w = 1; base = o1; }
        else if (i < o3) { w = 2; base = o2; }
        else             { w = 3; base = o3; }
        rl[i] = rlw[w * 512 + i - base];
    }
    __syncthreads();

    // ---- waves fully independent from here ----
    const int ml = lane & 15;
    const int q  = lane >> 4;
    const float* Wg = W + (size_t)task * KDIM * NDIM + c0 + ml;   // lane's B column

    for (int rg = wv; rg * 16 < count; rg += 4) {
        const int rr = rg * 16 + ml;
        const int rowm = rl[(rr < count) ? rr : 0];
        const float* xrow = x + (size_t)rowm * KDIM + q * 8;

        f32x4 acc = {};
        #pragma unroll 2
        for (int kf = 0; kf < 16; ++kf) {
            const int k0 = kf * 32;
            // B: 8 dword gathers, k = k0+q*8+j, col = c0+ml
            const float* wp = Wg + (size_t)(k0 + q * 8) * NDIM;
            float b[8];
            #pragma unroll
            for (int j = 0; j < 8; ++j) b[j] = wp[(size_t)j * NDIM];
            // A: 2 float4 loads, k = k0+q*8 .. +7
            const float4 a0 = *(const float4*)(xrow + k0);
            const float4 a1 = *(const float4*)(xrow + k0 + 4);

            f16x8 af, bf;
            af[0] = (_Float16)a0.x; af[1] = (_Float16)a0.y;
            af[2] = (_Float16)a0.z; af[3] = (_Float16)a0.w;
            af[4] = (_Float16)a1.x; af[5] = (_Float16)a1.y;
            af[6] = (_Float16)a1.z; af[7] = (_Float16)a1.w;
            #pragma unroll
            for (int j = 0; j < 8; ++j) bf[j] = (_Float16)b[j];

            acc = __builtin_amdgcn_mfma_f32_16x16x32_f16(af, bf, acc, 0, 0, 0);
        }

        // ---- store: D row = q*4+rg2 (wave-local), col = ml
        #pragma unroll
        for (int rg2 = 0; rg2 < 4; ++rg2) {
            const int rr2 = rg * 16 + q * 4 + rg2;
            if (rr2 < count)
                out[(size_t)rl[rr2] * NDIM + c0 + ml] = acc[rg2];
        }
    }
}

extern "C" void kernel_launch(void* const* d_in, const int* in_sizes, int n_in,
                              void* d_out, int out_size, void* d_ws, size_t ws_size,
                              hipStream_t stream) {
    const float* x    = (const float*)d_in[0];
    const int*   tids = (const int*)d_in[1];
    const float* W    = (const float*)d_in[2];
    float*       out  = (float*)d_out;
    const int n_rows  = in_sizes[1];   // 2048

    k_fused<<<dim3(NDIM / NCOL, 64), dim3(256), 0, stream>>>(x, tids, W, out, n_rows);
}

// Round 8
// 119.118 us; speedup vs baseline: 1.1069x; 1.1051x over previous
//
#include <hip/hip_runtime.h>

// LearnedTaskSpecificLinear: out[n,o] = sum_i x[n,i] * W[task_ids[n], i, o]
// x: [2048,512] f32, task_ids: [2048] i32, W: [64,512,512] f32, out: [2048,512] f32
//
// Round 8: two kernels; hot kernel is barrier-free, LDS-free, wave-autonomous.
//   K1 (1 block): histogram tids -> padded 16-row groups:
//       prow[192*16] (ushort row ids, 0xFFFF pad), gtask[192] (-1 = unused).
//   K2: grid (16 col-chunks of 32, 48 group-quads) x 256 thr; wave wv takes
//       group blockIdx.y*4+wv = 16 rows x 32 cols x K=512 (2x16 MFMA).
//       A-frags: float4 from x (row = prow[g*16+ml]); B-frags: 16 dword
//       gathers/kf at cols c0+ml, c0+16+ml -> full 128-B lines (no overfetch).
//       No __syncthreads anywhere; store rows via __shfl. W re-reads across
//       groups of one task come from L3 (W fits in 256 MB).

#define NDIM 512
#define KDIM 512
#define MAXG 192

typedef _Float16 f16x8 __attribute__((ext_vector_type(8)));
typedef float    f32x4 __attribute__((ext_vector_type(4)));

__global__ __launch_bounds__(256) void k_groups(
    const int* __restrict__ tids, int n_rows,
    int* __restrict__ gtask, unsigned short* __restrict__ prow)
{
    __shared__ int cnt[64], pos[64], gbase[64];
    const int tid = threadIdx.x;
    if (tid < 64) { cnt[tid] = 0; pos[tid] = 0; }
    __syncthreads();
    for (int i = tid; i < n_rows; i += 256)
        atomicAdd(&cnt[tids[i]], 1);
    __syncthreads();
    if (tid == 0) {
        int off = 0;
        for (int t = 0; t < 64; ++t) {
            gbase[t] = off;
            off += (cnt[t] + 15) >> 4;
        }
    }
    __syncthreads();
    for (int i = tid; i < MAXG * 16; i += 256) prow[i] = 0xFFFFu;
    if (tid < MAXG) gtask[tid] = -1;
    __syncthreads();          // prow/gtask fills done before scatter & gtask set
    if (tid < 64) {
        const int ng = (cnt[tid] + 15) >> 4;
        for (int g = 0; g < ng; ++g) gtask[gbase[tid] + g] = tid;
    }
    for (int i = tid; i < n_rows; i += 256) {
        const int t = tids[i];
        const int p = atomicAdd(&pos[t], 1);
        prow[gbase[t] * 16 + p] = (unsigned short)i;
    }
}

__global__ __launch_bounds__(256, 4) void k_gemm(
    const float* __restrict__ x, const float* __restrict__ W,
    const int* __restrict__ gtask, const unsigned short* __restrict__ prow,
    float* __restrict__ out)
{
    const int tid  = threadIdx.x;
    const int lane = tid & 63;
    const int wv   = tid >> 6;
    const int ml   = lane & 15;
    const int q    = lane >> 4;
    const int c0   = blockIdx.x * 32;
    const int g    = blockIdx.y * 4 + wv;

    const int task = gtask[g];
    if (task < 0) return;                     // wave-uniform; no barriers in kernel

    const int rowreg = prow[g * 16 + ml];     // 0xFFFF = pad
    const int xrow   = (rowreg == 0xFFFF) ? 0 : rowreg;
    const float* xp = x + (size_t)xrow * KDIM + q * 8;
    const float* Wp = W + (size_t)task * KDIM * NDIM + (size_t)(q * 8) * NDIM + c0 + ml;

    f32x4 acc0 = {}, acc1 = {};
    #pragma unroll 2
    for (int kf = 0; kf < 16; ++kf) {
        const float* wk = Wp + (size_t)kf * 32 * NDIM;
        float b0[8], b1[8];
        #pragma unroll
        for (int j = 0; j < 8; ++j) {
            b0[j] = wk[(size_t)j * NDIM];
            b1[j] = wk[(size_t)j * NDIM + 16];
        }
        const float4 a0 = *(const float4*)(xp + kf * 32);
        const float4 a1 = *(const float4*)(xp + kf * 32 + 4);

        f16x8 af, bf0, bf1;
        af[0] = (_Float16)a0.x; af[1] = (_Float16)a0.y;
        af[2] = (_Float16)a0.z; af[3] = (_Float16)a0.w;
        af[4] = (_Float16)a1.x; af[5] = (_Float16)a1.y;
        af[6] = (_Float16)a1.z; af[7] = (_Float16)a1.w;
        #pragma unroll
        for (int j = 0; j < 8; ++j) {
            bf0[j] = (_Float16)b0[j];
            bf1[j] = (_Float16)b1[j];
        }
        acc0 = __builtin_amdgcn_mfma_f32_16x16x32_f16(af, bf0, acc0, 0, 0, 0);
        acc1 = __builtin_amdgcn_mfma_f32_16x16x32_f16(af, bf1, acc1, 0, 0, 0);
    }

    // D layout: row = q*4+r2 (group-local), col = ml (+16). Row ids via shfl
    // (lanes 0..15 have ml == lane, so lane src holds prow[g*16+src]).
    #pragma unroll
    for (int r2 = 0; r2 < 4; ++r2) {
        const int src  = q * 4 + r2;
        const int orow = __shfl(rowreg, src);
        if (orow != 0xFFFF) {
            out[(size_t)orow * NDIM + c0 + ml]      = acc0[r2];
            out[(size_t)orow * NDIM + c0 + 16 + ml] = acc1[r2];
        }
    }
}

extern "C" void kernel_launch(void* const* d_in, const int* in_sizes, int n_in,
                              void* d_out, int out_size, void* d_ws, size_t ws_size,
                              hipStream_t stream) {
    const float* x    = (const float*)d_in[0];
    const int*   tids = (const int*)d_in[1];
    const float* W    = (const float*)d_in[2];
    float*       out  = (float*)d_out;
    const int n_rows  = in_sizes[1];   // 2048

    int*            gtask = (int*)d_ws;                              // 192 ints
    unsigned short* prow  = (unsigned short*)((char*)d_ws + 1024);   // 192*16 ushort

    k_groups<<<dim3(1), dim3(256), 0, stream>>>(tids, n_rows, gtask, prow);
    k_gemm<<<dim3(NDIM / 32, MAXG / 4), dim3(256), 0, stream>>>(x, W, gtask, prow, out);
}